// Round 1
// baseline (986.362 us; speedup 1.0000x reference)
//
#include <hip/hip_runtime.h>
#include <stdint.h>

#define NB 64      // batch
#define NP 576     // patches
#define ND 768     // dim
#define NG 64      // groups
#define NN 65      // groups + 1 (cls)
#define NSTEPS 8
#define FLOORV 1.0e-4
#define EPSV   1.0e-4
#define DTV    0.1
#define GAMMAV 0.1
#define KEEPC  288  // max(1, round(576*0.5))

// ---------------------------------------------------------------- K1: group means
__global__ __launch_bounds__(256) void k_group_means(const float* __restrict__ tokens,
                                                     const float* __restrict__ cls,
                                                     float* __restrict__ nodes,
                                                     const int* __restrict__ ghp,
                                                     const int* __restrict__ gwp) {
    int bx = blockIdx.x;
    int b = bx / NN, n = bx - b * NN;
    int tid = threadIdx.x;
    float* orow = nodes + (size_t)bx * ND;
    if (n == 0) {
        for (int d = tid; d < ND; d += 256) orow[d] = cls[(size_t)b * ND + d];
        return;
    }
    int grid_h = *ghp, grid_w = *gwp;
    int gh = (grid_h + 7) / 8, gw = (grid_w + 7) / 8;
    int g = n - 1, gr = g >> 3, gc = g & 7;
    int r0 = gr * gh, r1 = (gr == 7) ? grid_h : min((gr + 1) * gh, grid_h);
    int c0 = gc * gw, c1 = (gc == 7) ? grid_w : min((gc + 1) * gw, grid_w);
    int cnt = (r1 > r0 && c1 > c0) ? (r1 - r0) * (c1 - c0) : 0;
    float cf = (float)max(cnt, 1);
    const float* tb = tokens + (size_t)b * NP * ND;
    for (int d = tid; d < ND; d += 256) {
        float acc = 0.f;
        for (int r = r0; r < r1; ++r)
            for (int c = c0; c < c1; ++c)
                acc += tb[(size_t)(r * grid_w + c) * ND + d];
        orow[d] = acc / cf;
    }
}

// ---------------------------------------------------------------- K2: proj = nodes @ W^T (NT gemm)
// A: (NB*NN) x ND row-major, Bm: ND x ND row-major (W[e][d]), Cm[r][e] = sum_d A[r][d]*W[e][d]
__global__ __launch_bounds__(256) void k_gemm_nt(const float* __restrict__ A,
                                                 const float* __restrict__ Bm,
                                                 float* __restrict__ Cm) {
    __shared__ float As[32][68];
    __shared__ float Bs[32][68];
    int tid = threadIdx.x;
    int m0 = blockIdx.x * 64, n0 = blockIdx.y * 64;
    int tx = tid & 15, ty = tid >> 4;
    float acc[4][4];
#pragma unroll
    for (int i = 0; i < 4; ++i)
#pragma unroll
        for (int j = 0; j < 4; ++j) acc[i][j] = 0.f;
    int lrow = tid >> 3, lq = tid & 7;
    for (int k0 = 0; k0 < ND; k0 += 32) {
#pragma unroll
        for (int l = 0; l < 2; ++l) {
            int row = lrow + l * 32;
            float4 va = *(const float4*)&A[(size_t)(m0 + row) * ND + k0 + lq * 4];
            As[lq * 4 + 0][row] = va.x; As[lq * 4 + 1][row] = va.y;
            As[lq * 4 + 2][row] = va.z; As[lq * 4 + 3][row] = va.w;
            float4 vb = *(const float4*)&Bm[(size_t)(n0 + row) * ND + k0 + lq * 4];
            Bs[lq * 4 + 0][row] = vb.x; Bs[lq * 4 + 1][row] = vb.y;
            Bs[lq * 4 + 2][row] = vb.z; Bs[lq * 4 + 3][row] = vb.w;
        }
        __syncthreads();
#pragma unroll
        for (int kk = 0; kk < 32; ++kk) {
            float4 a4 = *(const float4*)&As[kk][ty * 4];
            float4 b4 = *(const float4*)&Bs[kk][tx * 4];
            float av[4] = {a4.x, a4.y, a4.z, a4.w};
            float bv[4] = {b4.x, b4.y, b4.z, b4.w};
#pragma unroll
            for (int i = 0; i < 4; ++i)
#pragma unroll
                for (int j = 0; j < 4; ++j) acc[i][j] += av[i] * bv[j];
        }
        __syncthreads();
    }
#pragma unroll
    for (int i = 0; i < 4; ++i) {
        float4 o = make_float4(acc[i][0], acc[i][1], acc[i][2], acc[i][3]);
        *(float4*)&Cm[(size_t)(m0 + ty * 4 + i) * ND + n0 + tx * 4] = o;
    }
}

// ---------------------------------------------------------------- K3: row-normalize proj, sq = sum(projN^2)
__global__ __launch_bounds__(256) void k_normalize(float* __restrict__ proj, float* __restrict__ sqv) {
    int r = blockIdx.x, tid = threadIdx.x;
    __shared__ double red[8];
    __shared__ float invs;
    float* row = proj + (size_t)r * ND;
    double s = 0.0;
    for (int d = tid; d < ND; d += 256) { double v = (double)row[d]; s += v * v; }
#pragma unroll
    for (int off = 32; off; off >>= 1) s += __shfl_down(s, off, 64);
    int wid = tid >> 6, lane = tid & 63;
    if (lane == 0) red[wid] = s;
    __syncthreads();
    if (tid == 0) invs = (float)(1.0 / fmax(sqrt(red[0] + red[1] + red[2] + red[3]), 1e-12));
    __syncthreads();
    float inv = invs;
    double s2 = 0.0;
    for (int d = tid; d < ND; d += 256) {
        float v = row[d] * inv; row[d] = v; s2 += (double)v * (double)v;
    }
#pragma unroll
    for (int off = 32; off; off >>= 1) s2 += __shfl_down(s2, off, 64);
    __syncthreads();
    if (lane == 0) red[wid] = s2;
    __syncthreads();
    if (tid == 0) sqv[r] = (float)(red[0] + red[1] + red[2] + red[3]);
}

// ---------------------------------------------------------------- K4: C init = with_floor(exp(-d2)), write d_hist[:,0]
__global__ __launch_bounds__(256) void k_pairwise(const float* __restrict__ proj,
                                                  const float* __restrict__ sqv,
                                                  float* __restrict__ dhist) {
    int b = blockIdx.x, tid = threadIdx.x;
    int tx = tid & 15, ty = tid >> 4;
    __shared__ float Ps[NN][65];
    float acc[5][5];
#pragma unroll
    for (int a = 0; a < 5; ++a)
#pragma unroll
        for (int c = 0; c < 5; ++c) acc[a][c] = 0.f;
    const float* Pb = proj + (size_t)b * NN * ND;
    for (int k0 = 0; k0 < ND; k0 += 64) {
        __syncthreads();
        for (int idx = tid; idx < NN * 64; idx += 256) {
            int i = idx >> 6, kk = idx & 63;
            Ps[i][kk] = Pb[(size_t)i * ND + k0 + kk];
        }
        __syncthreads();
        for (int kk = 0; kk < 64; ++kk) {
            float av[5], bv[5];
#pragma unroll
            for (int a = 0; a < 5; ++a) { int i = ty + 16 * a; av[a] = (i < NN) ? Ps[i][kk] : 0.f; }
#pragma unroll
            for (int c = 0; c < 5; ++c) { int j = tx + 16 * c; bv[c] = (j < NN) ? Ps[j][kk] : 0.f; }
#pragma unroll
            for (int a = 0; a < 5; ++a)
#pragma unroll
                for (int c = 0; c < 5; ++c) acc[a][c] += av[a] * bv[c];
        }
    }
#pragma unroll
    for (int a = 0; a < 5; ++a)
#pragma unroll
        for (int c = 0; c < 5; ++c) {
            int i = ty + 16 * a, j = tx + 16 * c;
            if (i < NN && j < NN) {
                float d2 = fmaxf(sqv[b * NN + i] + sqv[b * NN + j] - 2.0f * acc[a][c], 0.f);
                double cv = exp(-(double)d2);   // TAU = 1
                float cf = (i == j) ? 0.f : fmaxf((float)cv, (float)FLOORV);
                dhist[(size_t)b * 9 * NN * NN + (size_t)i * NN + j] = cf;
            }
        }
}

// ---------------------------------------------------------------- K5: 8-step physarum dynamics (per-batch block)
__global__ __launch_bounds__(256) void k_dynamics(float* __restrict__ dhist,
                                                  float* __restrict__ qhist,
                                                  double* __restrict__ part) {
    int b = blockIdx.x, tid = threadIdx.x;
    __shared__ float Cd[NN][NN + 1];      // current conductance (fp32, like reference)
    __shared__ double Aug[NN][NN + 2];    // augmented system (fp64), col NN = rhs
    __shared__ double pv[NN];
    __shared__ double red[8];
    float* C0 = dhist + (size_t)b * 9 * NN * NN;
    for (int idx = tid; idx < NN * NN; idx += 256)
        Cd[idx / NN][idx % NN] = C0[idx];
    double stable = 0.0, sparse = 0.0;
    for (int step = 0; step < NSTEPS; ++step) {
        __syncthreads();
        if (tid < NN) {                 // deg + diagonal
            double s = 0.0;
            for (int j = 0; j < NN; ++j) s += (double)Cd[tid][j];
            Aug[tid][tid] = s + EPSV;
        }
        for (int idx = tid; idx < NN * (NN + 1); idx += 256) {
            int i = idx / (NN + 1), j = idx - i * (NN + 1);
            if (j == NN) Aug[i][NN] = (i == 0) ? 1.0 : (-1.0 / NG);
            else if (i != j) Aug[i][j] = -(double)Cd[i][j];
        }
        __syncthreads();
        // forward elimination (no pivoting; strictly diagonally dominant)
        for (int k = 0; k < NN - 1; ++k) {
            int i = k + 1 + (tid >> 2);
            if (i < NN) {
                double f = Aug[i][k] / Aug[k][k];
                for (int j = k + 1 + (tid & 3); j <= NN; j += 4)
                    Aug[i][j] -= f * Aug[k][j];
            }
            __syncthreads();
        }
        // back substitution on wave 0
        if (tid < 64) {
            for (int i = NN - 1; i >= 0; --i) {
                double s = 0.0;
                int j = i + 1 + tid;
                if (j < NN) s = Aug[i][j] * pv[j];
#pragma unroll
                for (int off = 32; off; off >>= 1) s += __shfl_down(s, off, 64);
                if (tid == 0) pv[i] = (Aug[i][NN] - s) / Aug[i][i];
            }
        }
        __syncthreads();
        float* qout = qhist + ((size_t)b * NSTEPS + step) * NN * NN;
        float* dout = dhist + ((size_t)b * 9 + step + 1) * NN * NN;
        for (int idx = tid; idx < NN * NN; idx += 256) {
            int i = idx / NN, j = idx - i * NN;
            float cf = Cd[i][j];
            double cij = (double)cf;
            double fl = cij * (pv[i] - pv[j]);
            qout[idx] = (float)fl;
            double r = fabs(fl); r = r / (1.0 + r);
            double cn = cij + DTV * (r - GAMMAV * cij);
            float cnf = (i == j) ? 0.0f : (float)fmax(cn, FLOORV);
            Cd[i][j] = cnf;
            dout[idx] = cnf;
            stable += fabs((double)cnf - cij);
            if (step == NSTEPS - 1 && i > 0 && j > 0) sparse += (double)cnf;
        }
    }
#pragma unroll
    for (int off = 32; off; off >>= 1) {
        stable += __shfl_down(stable, off, 64);
        sparse += __shfl_down(sparse, off, 64);
    }
    int wid = tid >> 6, lane = tid & 63;
    __syncthreads();
    if (lane == 0) { red[wid] = stable; red[4 + wid] = sparse; }
    __syncthreads();
    if (tid == 0) {
        part[b]      = red[4] + red[5] + red[6] + red[7];  // sparse partial
        part[NB + b] = red[0] + red[1] + red[2] + red[3];  // stable partial
    }
}

// ---------------------------------------------------------------- K6: scores, top-k masks, gid, group_scores
__global__ __launch_bounds__(256) void k_scores(const float* __restrict__ qhist,
                                                const float* __restrict__ local,
                                                const int* __restrict__ ghp,
                                                const int* __restrict__ gwp,
                                                float* __restrict__ keep,
                                                float* __restrict__ patch,
                                                float* __restrict__ gidout,
                                                float* __restrict__ gsout) {
    int b = blockIdx.x, tid = threadIdx.x;
    __shared__ double gf[NG];
    __shared__ double ts[NP];
    __shared__ double red[8];
    __shared__ double stats[2];
    if (tid < NG) {
        const float* qrow = qhist + ((size_t)b * NSTEPS + (NSTEPS - 1)) * NN * NN + (size_t)(tid + 1) * NN;
        double s = 0.0;
        for (int j = 0; j < NN; ++j) s += fabs((double)qrow[j]);
        gf[tid] = s;
    }
    __syncthreads();
    if (tid < 64) {
        double v = gf[tid];
        double s = v;
#pragma unroll
        for (int off = 32; off; off >>= 1) s += __shfl_down(s, off, 64);
        double mean = __shfl(s, 0, 64) / (double)NG;
        double d = v - mean, ss = d * d;
#pragma unroll
        for (int off = 32; off; off >>= 1) ss += __shfl_down(ss, off, 64);
        if (tid == 0) { stats[0] = mean; stats[1] = 1.0 / fmax(sqrt(ss / (NG - 1)), 1e-6); }
    }
    const float* lrow = local + (size_t)b * NP;
    double s1 = 0.0;
    for (int p = tid; p < NP; p += 256) s1 += (double)lrow[p];
#pragma unroll
    for (int off = 32; off; off >>= 1) s1 += __shfl_down(s1, off, 64);
    int wid = tid >> 6, lane = tid & 63;
    if (lane == 0) red[wid] = s1;
    __syncthreads();
    double lmean = (red[0] + red[1] + red[2] + red[3]) / (double)NP;
    double s2 = 0.0;
    for (int p = tid; p < NP; p += 256) { double d = (double)lrow[p] - lmean; s2 += d * d; }
#pragma unroll
    for (int off = 32; off; off >>= 1) s2 += __shfl_down(s2, off, 64);
    __syncthreads();
    if (lane == 0) red[wid] = s2;
    __syncthreads();
    double linv = 1.0 / fmax(sqrt((red[0] + red[1] + red[2] + red[3]) / (double)(NP - 1)), 1e-6);
    double gmean = stats[0], ginv = stats[1];
    int grid_h = *ghp, grid_w = *gwp;
    int gh = (grid_h + 7) / 8, gw = (grid_w + 7) / 8;
    for (int p = tid; p < NP; p += 256) {
        int row = p / grid_w, col = p - row * grid_w;
        int g = min(row / gh, 7) * 8 + min(col / gw, 7);
        double gsc = (gf[g] - gmean) * ginv;
        double lsc = ((double)lrow[p] - lmean) * linv;
        ts[p] = gsc + 0.5 * lsc;  // FLOW_W=1, LOCAL_W=0.5
        gidout[(size_t)b * NP + p] = (float)g;
        gsout[(size_t)b * NP + p]  = (float)gsc;
    }
    __syncthreads();
    for (int p = tid; p < NP; p += 256) {
        double sp = ts[p];
        int c = 0;
        for (int q = 0; q < NP; ++q) {
            double v = ts[q];
            c += (v > sp) || (v == sp && q < p);
        }
        float kf = (c < KEEPC) ? 1.0f : 0.0f;
        patch[(size_t)b * NP + p] = kf;
        keep[(size_t)b * (NP + 1) + 1 + p] = kf;
    }
    if (tid == 0) keep[(size_t)b * (NP + 1)] = 1.0f;
}

// ---------------------------------------------------------------- K7: routing rows
__global__ void k_routing(const float* __restrict__ dhist, float* __restrict__ rout) {
    int b = blockIdx.x, tid = threadIdx.x;  // 64 threads
    const float* Crow = dhist + ((size_t)b * 9 + 8) * NN * NN + (size_t)(tid + 1) * NN + 1;
    double s = 0.0;
    for (int j = 0; j < NG; ++j) s += (double)Crow[j];
    double inv = 1.0 / fmax(s, 1e-6);
    float* orow = rout + ((size_t)b * NG + tid) * NG;
    for (int j = 0; j < NG; ++j) orow[j] = (float)((double)Crow[j] * inv);
}

// ---------------------------------------------------------------- K8: aux scalar reduction
__global__ void k_aux(const double* __restrict__ part, float* __restrict__ osp, float* __restrict__ ost) {
    int tid = threadIdx.x;  // 64 threads
    double sp = part[tid], st = part[NB + tid];
#pragma unroll
    for (int off = 32; off; off >>= 1) {
        sp += __shfl_down(sp, off, 64);
        st += __shfl_down(st, off, 64);
    }
    if (tid == 0) { *osp = (float)(sp / NB); *ost = (float)(st / NB); }
}

// ----------------------------------------------------------------
extern "C" void kernel_launch(void* const* d_in, const int* in_sizes, int n_in,
                              void* d_out, int out_size, void* d_ws, size_t ws_size,
                              hipStream_t stream) {
    const float* tokens = (const float*)d_in[0];
    const float* cls    = (const float*)d_in[1];
    const float* W      = (const float*)d_in[2];
    const float* local  = (const float*)d_in[3];
    const int* ghp = (const int*)d_in[4];
    const int* gwp = (const int*)d_in[5];

    float* out = (float*)d_out;
    float* o_keep  = out;                                   // NB x (NP+1)
    float* o_patch = o_keep + (size_t)NB * (NP + 1);        // NB x NP
    float* o_gid   = o_patch + (size_t)NB * NP;             // NB x NP
    float* o_gs    = o_gid + (size_t)NB * NP;               // NB x NP
    float* o_dh    = o_gs + (size_t)NB * NP;                // NB x 9 x NN x NN
    float* o_qh    = o_dh + (size_t)NB * 9 * NN * NN;       // NB x 8 x NN x NN
    float* o_rt    = o_qh + (size_t)NB * NSTEPS * NN * NN;  // NB x NG x NG
    float* o_sp    = o_rt + (size_t)NB * NG * NG;           // scalar
    float* o_st    = o_sp + 1;                              // scalar

    float* nodes = (float*)d_ws;                            // NB*NN x ND
    float* proj  = nodes + (size_t)NB * NN * ND;            // NB*NN x ND
    float* sqv   = proj + (size_t)NB * NN * ND;             // NB*NN
    double* part = (double*)(((uintptr_t)(sqv + NB * NN) + 15) & ~(uintptr_t)15);  // 2*NB

    k_group_means<<<NB * NN, 256, 0, stream>>>(tokens, cls, nodes, ghp, gwp);
    dim3 g2((NB * NN) / 64, ND / 64);
    k_gemm_nt<<<g2, 256, 0, stream>>>(nodes, W, proj);
    k_normalize<<<NB * NN, 256, 0, stream>>>(proj, sqv);
    k_pairwise<<<NB, 256, 0, stream>>>(proj, sqv, o_dh);
    k_dynamics<<<NB, 256, 0, stream>>>(o_dh, o_qh, part);
    k_scores<<<NB, 256, 0, stream>>>(o_qh, local, ghp, gwp, o_keep, o_patch, o_gid, o_gs);
    k_routing<<<NB, 64, 0, stream>>>(o_dh, o_rt);
    k_aux<<<1, 64, 0, stream>>>(part, o_sp, o_st);
}